// Round 1
// baseline (62.260 us; speedup 1.0000x reference)
//
#include <hip/hip_runtime.h>

#define T_STEPS 200
#define BATCH 32
#define N_IN 10000
#define N_OUT 3
#define ROWS (T_STEPS * BATCH)        // 6400
#define PROJ_N (T_STEPS * BATCH * N_OUT) // 19200

// Kernel 1: proj[row*3+o] = sum_i spikes[row, i] * W[o, i]
// One block per row (t*B+b). 256 threads, float4 loads, 3 accumulators/thread.
__global__ __launch_bounds__(256) void proj_kernel(
    const float* __restrict__ spikes,
    const float* __restrict__ W,
    float* __restrict__ proj)   // [ROWS*3], written into spk_rec region of d_out
{
    const int row = blockIdx.x;
    const int tid = threadIdx.x;

    const float4* __restrict__ srow = reinterpret_cast<const float4*>(spikes + (size_t)row * N_IN);
    const float4* __restrict__ W0 = reinterpret_cast<const float4*>(W);
    const float4* __restrict__ W1 = reinterpret_cast<const float4*>(W + N_IN);
    const float4* __restrict__ W2 = reinterpret_cast<const float4*>(W + 2 * N_IN);

    float a0 = 0.f, a1 = 0.f, a2 = 0.f;
    // N_IN/4 = 2500 float4 elements per row
    #pragma unroll 2
    for (int i = tid; i < N_IN / 4; i += 256) {
        float4 s  = srow[i];
        float4 w0 = W0[i];
        float4 w1 = W1[i];
        float4 w2 = W2[i];
        a0 += s.x * w0.x + s.y * w0.y + s.z * w0.z + s.w * w0.w;
        a1 += s.x * w1.x + s.y * w1.y + s.z * w1.z + s.w * w1.w;
        a2 += s.x * w2.x + s.y * w2.y + s.z * w2.z + s.w * w2.w;
    }

    // wave (64-lane) reduction
    for (int off = 32; off > 0; off >>= 1) {
        a0 += __shfl_down(a0, off);
        a1 += __shfl_down(a1, off);
        a2 += __shfl_down(a2, off);
    }

    __shared__ float red0[4], red1[4], red2[4];
    const int wave = tid >> 6;
    if ((tid & 63) == 0) { red0[wave] = a0; red1[wave] = a1; red2[wave] = a2; }
    __syncthreads();
    if (tid == 0) {
        float r0 = red0[0] + red0[1] + red0[2] + red0[3];
        float r1 = red1[0] + red1[1] + red1[2] + red1[3];
        float r2 = red2[0] + red2[1] + red2[2] + red2[3];
        proj[row * 3 + 0] = r0;
        proj[row * 3 + 1] = r1;
        proj[row * 3 + 2] = r2;
    }
}

// Kernel 2: sequential AdaMem scan over T for each of the 96 (b,o) states.
// proj lives in the spk_rec region of d_out; each thread reads proj[t,idx]
// before overwriting that same element with the spike value.
__global__ __launch_bounds__(128) void scan_kernel(
    const float* __restrict__ bias,
    float* __restrict__ out)    // [2*PROJ_N]: spk_rec then mem_rec
{
    const int idx = threadIdx.x;            // b*3 + o
    if (idx >= BATCH * N_OUT) return;

    const float bo = bias[idx % N_OUT];
    float* __restrict__ spk_rec = out;               // also holds proj on entry
    float* __restrict__ mem_rec = out + PROJ_N;

    float mem = 0.0f;
    float thr = 1.0f;   // THR_INIT

    for (int t = 0; t < T_STEPS; ++t) {
        const int e = t * (BATCH * N_OUT) + idx;
        float x = spk_rec[e] + bo;                  // proj + bias
        mem = 0.99f * mem + x;                      // BETA leaky integration
        float spk = (mem > thr) ? 1.0f : 0.0f;
        mem = mem - spk * thr;                      // reset by subtraction
        thr = 0.95f * thr + 5.0f * spk;             // BASE_THR=0 adaptive threshold
        spk_rec[e] = spk;
        mem_rec[e] = mem;
    }
}

extern "C" void kernel_launch(void* const* d_in, const int* in_sizes, int n_in,
                              void* d_out, int out_size, void* d_ws, size_t ws_size,
                              hipStream_t stream) {
    const float* spikes = (const float*)d_in[0];   // [200,32,10000]
    const float* W      = (const float*)d_in[1];   // [3,10000]
    const float* b      = (const float*)d_in[2];   // [3]
    float* out = (float*)d_out;                    // [2,200,32,3] flat

    proj_kernel<<<ROWS, 256, 0, stream>>>(spikes, W, out /* proj -> spk region */);
    scan_kernel<<<1, 128, 0, stream>>>(b, out);
}

// Round 2
// 55.622 us; speedup vs baseline: 1.1194x; 1.1194x over previous
//
#include <hip/hip_runtime.h>

#define T_STEPS 200
#define BATCH 32
#define N_IN 10000
#define N_OUT 3
#define ROWS (T_STEPS * BATCH)            // 6400
#define STATES (BATCH * N_OUT)            // 96
#define PROJ_N (ROWS * N_OUT)             // 19200
#define NV4 (N_IN / 4)                    // 2500 float4 per row
#define RPB 4                             // rows per block in proj kernel

__device__ __forceinline__ float dot4(float4 a, float4 b) {
    return a.x * b.x + a.y * b.y + a.z * b.z + a.w * b.w;
}

// Kernel 1: proj[row*3+o] = dot(spikes[row,:], W[o,:]) + b[o]
// RPB consecutive rows per block: W float4 loaded once, reused for RPB rows.
__global__ __launch_bounds__(256) void proj_kernel(
    const float* __restrict__ spikes,
    const float* __restrict__ W,
    const float* __restrict__ bias,
    float* __restrict__ proj)             // [ROWS*3] in d_ws
{
    const int row0 = blockIdx.x * RPB;
    const int tid = threadIdx.x;

    const float4* __restrict__ s0 = reinterpret_cast<const float4*>(spikes + (size_t)row0 * N_IN);
    const float4* __restrict__ W0 = reinterpret_cast<const float4*>(W);
    const float4* __restrict__ W1 = reinterpret_cast<const float4*>(W + N_IN);
    const float4* __restrict__ W2 = reinterpret_cast<const float4*>(W + 2 * N_IN);

    float acc[RPB][3];
    #pragma unroll
    for (int r = 0; r < RPB; ++r)
        #pragma unroll
        for (int o = 0; o < 3; ++o) acc[r][o] = 0.f;

    #pragma unroll 2
    for (int i = tid; i < NV4; i += 256) {
        float4 w0 = W0[i];
        float4 w1 = W1[i];
        float4 w2 = W2[i];
        #pragma unroll
        for (int r = 0; r < RPB; ++r) {
            float4 s = s0[(size_t)r * NV4 + i];
            acc[r][0] += dot4(s, w0);
            acc[r][1] += dot4(s, w1);
            acc[r][2] += dot4(s, w2);
        }
    }

    // wave (64-lane) reduction of the 12 accumulators
    #pragma unroll
    for (int r = 0; r < RPB; ++r)
        #pragma unroll
        for (int o = 0; o < 3; ++o)
            for (int off = 32; off > 0; off >>= 1)
                acc[r][o] += __shfl_down(acc[r][o], off);

    __shared__ float red[4][RPB][3];
    const int wave = tid >> 6;
    if ((tid & 63) == 0) {
        #pragma unroll
        for (int r = 0; r < RPB; ++r)
            #pragma unroll
            for (int o = 0; o < 3; ++o)
                red[wave][r][o] = acc[r][o];
    }
    __syncthreads();
    if (tid < RPB * 3) {
        const int r = tid / 3, o = tid % 3;
        float s = red[0][r][o] + red[1][r][o] + red[2][r][o] + red[3][r][o];
        proj[(size_t)(row0 + r) * 3 + o] = s + bias[o];
    }
}

// Kernel 2: sequential AdaMem scan, one thread per (b,o) state.
// proj is a separate const buffer (d_ws) -> no aliasing with outputs;
// 8-deep prefetch pipelines the L2 loads.
__global__ __launch_bounds__(128) void scan_kernel(
    const float* __restrict__ proj,       // [T,96] in d_ws
    float* __restrict__ out)              // [2*PROJ_N]: spk_rec then mem_rec
{
    const int idx = threadIdx.x;          // b*3 + o
    if (idx >= STATES) return;

    float* __restrict__ spk_rec = out;
    float* __restrict__ mem_rec = out + PROJ_N;

    float mem = 0.0f;
    float thr = 1.0f;                     // THR_INIT

    float xb[8];
    for (int t0 = 0; t0 < T_STEPS; t0 += 8) {
        #pragma unroll
        for (int k = 0; k < 8; ++k)
            xb[k] = proj[(size_t)(t0 + k) * STATES + idx];
        #pragma unroll
        for (int k = 0; k < 8; ++k) {
            mem = 0.99f * mem + xb[k];               // leaky integration
            float spk = (mem > thr) ? 1.0f : 0.0f;   // fire
            mem -= spk * thr;                        // reset by subtraction
            thr = 0.95f * thr + 5.0f * spk;          // adaptive threshold (BASE_THR=0)
            const int e = (t0 + k) * STATES + idx;
            spk_rec[e] = spk;
            mem_rec[e] = mem;
        }
    }
}

extern "C" void kernel_launch(void* const* d_in, const int* in_sizes, int n_in,
                              void* d_out, int out_size, void* d_ws, size_t ws_size,
                              hipStream_t stream) {
    const float* spikes = (const float*)d_in[0];   // [200,32,10000]
    const float* W      = (const float*)d_in[1];   // [3,10000]
    const float* b      = (const float*)d_in[2];   // [3]
    float* out  = (float*)d_out;                   // [2,200,32,3] flat
    float* proj = (float*)d_ws;                    // [200,32,3] scratch

    proj_kernel<<<ROWS / RPB, 256, 0, stream>>>(spikes, W, b, proj);
    scan_kernel<<<1, 128, 0, stream>>>(proj, out);
}